// Round 11
// baseline (562.298 us; speedup 1.0000x reference)
//
#include <hip/hip_runtime.h>
#include <math.h>
#include <cstddef>

#define B_ 16
#define T_ 256
#define D_ 128
#define H_ 128
#define L_ 4
#define G_ 512          // 4*H
#define NC_ 10
#define EPS_ 1e-5f
#define C_ 16           // pipeline chunk (timesteps per flag)
#define NCHUNK_ (T_ / C_)

// padded LDS h layout: +4 floats per 32 -> rows of 144 floats; quarter q starts
// at q*36 floats (144B, 16B-aligned) -> zero conflicts
#define HROW_ 144
#define HOFF(k) ((k) + (((k) >> 5) << 2))

typedef float f4v __attribute__((ext_vector_type(4)));

// 8 x global_load_dwordx4 -> 32 floats resident (compiler cannot remat asm)
#define LOAD_W8(w, base)                                                   \
    asm volatile(                                                          \
        "global_load_dwordx4 %0, %8, off\n\t"                             \
        "global_load_dwordx4 %1, %8, off offset:16\n\t"                   \
        "global_load_dwordx4 %2, %8, off offset:32\n\t"                   \
        "global_load_dwordx4 %3, %8, off offset:48\n\t"                   \
        "global_load_dwordx4 %4, %8, off offset:64\n\t"                   \
        "global_load_dwordx4 %5, %8, off offset:80\n\t"                   \
        "global_load_dwordx4 %6, %8, off offset:96\n\t"                   \
        "global_load_dwordx4 %7, %8, off offset:112\n\t"                  \
        "s_waitcnt vmcnt(0)"                                               \
        : "=&v"(w[0]), "=&v"(w[1]), "=&v"(w[2]), "=&v"(w[3]),              \
          "=&v"(w[4]), "=&v"(w[5]), "=&v"(w[6]), "=&v"(w[7])               \
        : "v"(base)                                                        \
        : "memory")

// 32-k partial dot against pre-loaded h registers hv_[8]
#define DOT32R(dst_, warr_, hvarr_)                                        \
    {                                                                      \
        float d0_ = 0.f, d1_ = 0.f;                                        \
        _Pragma("unroll")                                                  \
        for (int j_ = 0; j_ < 8; j_++) {                                   \
            d0_ = fmaf(warr_[j_].x, hvarr_[j_].x, d0_);                    \
            d1_ = fmaf(warr_[j_].y, hvarr_[j_].y, d1_);                    \
            d0_ = fmaf(warr_[j_].z, hvarr_[j_].z, d0_);                    \
            d1_ = fmaf(warr_[j_].w, hvarr_[j_].w, d1_);                    \
        }                                                                  \
        dst_ = d0_ + d1_;                                                  \
    }

// ---------------- device helpers ----------------
__device__ __forceinline__ float sigmoid_(float x) {
    x = fminf(fmaxf(x, -30.f), 30.f);
    return 1.f / (1.f + __expf(-x));
}
__device__ __forceinline__ float tanh_(float x) {
    float ax = fminf(fabsf(x), 15.f);
    float e = __expf(2.f * ax);
    float t = 1.f - 2.f / (e + 1.f);
    return copysignf(t, x);
}
// single-thread spin: RELAXED polls + s_sleep, one final ACQUIRE for ordering
__device__ __forceinline__ void wait_ge_(int* p, int v) {
    if (__hip_atomic_load(p, __ATOMIC_RELAXED, __HIP_MEMORY_SCOPE_AGENT) < v) {
        do { __builtin_amdgcn_s_sleep(1); }
        while (__hip_atomic_load(p, __ATOMIC_RELAXED, __HIP_MEMORY_SCOPE_AGENT) < v);
    }
    (void)__hip_atomic_load(p, __ATOMIC_ACQUIRE, __HIP_MEMORY_SCOPE_AGENT);
}

// ---------------- stage 1: input normalize ----------------
__global__ __launch_bounds__(512) void stats_bd(const float* __restrict__ x,
                                                float* __restrict__ sum_bd,
                                                float* __restrict__ sq_bd) {
    int b = blockIdx.x;
    int tid = threadIdx.x;
    int d = tid & 127, r = tid >> 7;
    const float* xb = x + (size_t)b * T_ * D_;
    float s = 0.f, q = 0.f;
    for (int t = r; t < T_; t += 4) {
        float v = xb[t * D_ + d];
        s += v; q += v * v;
    }
    __shared__ float ls[512], lq[512];
    ls[tid] = s; lq[tid] = q;
    __syncthreads();
    if (r == 0) {
        s = ls[d] + ls[d + 128] + ls[d + 256] + ls[d + 384];
        q = lq[d] + lq[d + 128] + lq[d + 256] + lq[d + 384];
        sum_bd[b * 128 + d] = s;
        sq_bd[b * 128 + d] = q;
    }
}

__global__ __launch_bounds__(128) void stats_d(const float* __restrict__ sum_bd,
                                               const float* __restrict__ sq_bd,
                                               float* __restrict__ sdv) {
    int d = threadIdx.x;
    float s = 0.f, q = 0.f;
    for (int b = 0; b < B_; b++) { s += sum_bd[b * 128 + d]; q += sq_bd[b * 128 + d]; }
    float n = (float)(B_ * T_);
    float m = s / n;
    float varu = (q - n * m * m) / (n - 1.f);
    varu = fmaxf(varu, 0.f);
    sdv[d] = sqrtf(varu) + EPS_;
}

__global__ __launch_bounds__(256) void normalize_x(const float* __restrict__ x,
                                                   const float* __restrict__ sum_bd,
                                                   const float* __restrict__ sq_bd,
                                                   const float* __restrict__ sdv,
                                                   float* __restrict__ xn) {
    int idx = blockIdx.x * 256 + threadIdx.x;
    int d = idx & 127;
    int b = idx >> 15;
    int bd = b * 128 + d;
    float mu = sum_bd[bd] * (1.f / T_);
    float varT = sq_bd[bd] * (1.f / T_) - mu * mu;
    float s = sdv[d];
    float inv = rsqrtf(fmaxf(varT, 0.f) + EPS_ * s * s);
    xn[idx] = (x[idx] - mu) * inv;
}

// ---------------- generic K=128 GEMM (plain + A-normalized variant) ----------------
__global__ __launch_bounds__(256) void gemm_bias_k128(const float* __restrict__ A,
                                                      const float* __restrict__ Bw,
                                                      const float* __restrict__ b1,
                                                      const float* __restrict__ b2,
                                                      float* __restrict__ C, int N) {
    __shared__ __align__(16) float As[16][64];
    __shared__ __align__(16) float Bs[16][64];
    int tid = threadIdx.x;
    int m0 = blockIdx.x * 64, n0 = blockIdx.y * 64;
    int lr = tid >> 2;
    int lc = (tid & 3) << 2;
    int tm = (tid >> 4) << 2;
    int tn = (tid & 15) << 2;
    float acc[4][4] = {};
    const float* Arow = A + (size_t)(m0 + lr) * 128 + lc;
    const float* Brow = Bw + (size_t)(n0 + lr) * 128 + lc;
    for (int kb = 0; kb < 128; kb += 16) {
        float4 av = *(const float4*)(Arow + kb);
        float4 bv = *(const float4*)(Brow + kb);
        __syncthreads();
        As[lc + 0][lr] = av.x; As[lc + 1][lr] = av.y; As[lc + 2][lr] = av.z; As[lc + 3][lr] = av.w;
        Bs[lc + 0][lr] = bv.x; Bs[lc + 1][lr] = bv.y; Bs[lc + 2][lr] = bv.z; Bs[lc + 3][lr] = bv.w;
        __syncthreads();
#pragma unroll
        for (int k = 0; k < 16; k++) {
            float4 a4 = *(const float4*)&As[k][tm];
            float4 b4 = *(const float4*)&Bs[k][tn];
            float ar[4] = {a4.x, a4.y, a4.z, a4.w};
            float br[4] = {b4.x, b4.y, b4.z, b4.w};
#pragma unroll
            for (int i = 0; i < 4; i++)
#pragma unroll
                for (int j = 0; j < 4; j++)
                    acc[i][j] = fmaf(ar[i], br[j], acc[i][j]);
        }
    }
#pragma unroll
    for (int i = 0; i < 4; i++) {
        int row = m0 + tm + i;
#pragma unroll
        for (int j = 0; j < 4; j++) {
            int col = n0 + tn + j;
            float bias = b1[col] + (b2 ? b2[col] : 0.f);
            C[(size_t)row * N + col] = acc[i][j] + bias;
        }
    }
}

// A-normalized on load: Anorm[m][k] = (A[m][k] - mu[b*128+k]) * inv[b*128+k],
// b = m>>8. Fuses apply_in into the ph projection (no lnorm buffer).
__global__ __launch_bounds__(256) void gemm_norm_k128(const float* __restrict__ A,
                                                      const float* __restrict__ mu,
                                                      const float* __restrict__ inv,
                                                      const float* __restrict__ Bw,
                                                      const float* __restrict__ b1,
                                                      float* __restrict__ C, int N) {
    __shared__ __align__(16) float As[16][64];
    __shared__ __align__(16) float Bs[16][64];
    int tid = threadIdx.x;
    int m0 = blockIdx.x * 64, n0 = blockIdx.y * 64;
    int lr = tid >> 2;
    int lc = (tid & 3) << 2;
    int tm = (tid >> 4) << 2;
    int tn = (tid & 15) << 2;
    float acc[4][4] = {};
    int bidx = (m0 + lr) >> 8;
    const float* Arow = A + (size_t)(m0 + lr) * 128 + lc;
    const float* Brow = Bw + (size_t)(n0 + lr) * 128 + lc;
    const float* mup = mu + bidx * 128 + lc;
    const float* ivp = inv + bidx * 128 + lc;
    for (int kb = 0; kb < 128; kb += 16) {
        float4 av = *(const float4*)(Arow + kb);
        float4 m4 = *(const float4*)(mup + kb);
        float4 i4 = *(const float4*)(ivp + kb);
        av.x = (av.x - m4.x) * i4.x; av.y = (av.y - m4.y) * i4.y;
        av.z = (av.z - m4.z) * i4.z; av.w = (av.w - m4.w) * i4.w;
        float4 bv = *(const float4*)(Brow + kb);
        __syncthreads();
        As[lc + 0][lr] = av.x; As[lc + 1][lr] = av.y; As[lc + 2][lr] = av.z; As[lc + 3][lr] = av.w;
        Bs[lc + 0][lr] = bv.x; Bs[lc + 1][lr] = bv.y; Bs[lc + 2][lr] = bv.z; Bs[lc + 3][lr] = bv.w;
        __syncthreads();
#pragma unroll
        for (int k = 0; k < 16; k++) {
            float4 a4 = *(const float4*)&As[k][tm];
            float4 b4 = *(const float4*)&Bs[k][tn];
            float ar[4] = {a4.x, a4.y, a4.z, a4.w};
            float br[4] = {b4.x, b4.y, b4.z, b4.w};
#pragma unroll
            for (int i = 0; i < 4; i++)
#pragma unroll
                for (int j = 0; j < 4; j++)
                    acc[i][j] = fmaf(ar[i], br[j], acc[i][j]);
        }
    }
#pragma unroll
    for (int i = 0; i < 4; i++) {
        int row = m0 + tm + i;
#pragma unroll
        for (int j = 0; j < 4; j++) {
            int col = n0 + tn + j;
            C[(size_t)row * N + col] = acc[i][j] + b1[col];
        }
    }
}

// ---------------- chunk-pipelined 4-layer LSTM, quad row-sharing, C_=16 ----------------
__global__ __attribute__((amdgpu_waves_per_eu(2, 2))) __launch_bounds__(512)
void scan_pipe4(const float* __restrict__ g0,      // [B][T][G] layer-0 preacts
                const float* __restrict__ Wih, const float* __restrict__ Whh,
                const float* __restrict__ bih, const float* __restrict__ bhh,
                float* __restrict__ h_glob,        // [L][B][T][H]
                float* __restrict__ ring,          // [3][B][4][C_][G]
                int* __restrict__ flag_h,          // [L][B]
                int* __restrict__ flag_g) {        // [3][B]
    const int wg = blockIdx.x;
    const int tid = threadIdx.x;
    const int r = tid >> 2, q = tid & 3;

    if (wg < 64) {
        // ======== recurrent consumer (l, b) ========
        const int l = wg >> 4, b = wg & 15;
        __shared__ __align__(16) float hsh[2][HROW_];
        f4v w0[8], w1[8], w2[8], w3[8];
        const float* wl = Whh + (size_t)l * G_ * 128;
        LOAD_W8(w0, wl + ((size_t)(0 * 128 + r)) * 128 + q * 32);
        LOAD_W8(w1, wl + ((size_t)(1 * 128 + r)) * 128 + q * 32);
        LOAD_W8(w2, wl + ((size_t)(2 * 128 + r)) * 128 + q * 32);
        LOAD_W8(w3, wl + ((size_t)(3 * 128 + r)) * 128 + q * 32);
        float c = 0.f;
        if (tid < HROW_) hsh[0][tid] = 0.f;
        const float* g0p = g0 + (size_t)b * T_ * G_;
        const float* rsl = (l > 0) ? ring + ((size_t)(l - 1) * 16 + b) * (4 * C_ * G_) : ring;
        float* hob = h_glob + ((size_t)l * 16 + b) * T_ * 128;
        int* fg = (l > 0) ? flag_g + (l - 1) * 16 + b : flag_g;
        int* fh = flag_h + l * 16 + b;
        float hreg[C_];
        __syncthreads();

        for (int k = 0; k < NCHUNK_; k++) {
            if (l > 0) {
                if (tid == 0) wait_ge_(fg, k + 1);
                __syncthreads();
            }
#pragma unroll
            for (int half = 0; half < 2; half++) {
                // prefetch 8 steps of preacts for this thread's 4 gate rows
                float p0[8], p1[8], p2[8], p3[8];
#pragma unroll
                for (int s8 = 0; s8 < 8; s8++) {
                    int s = half * 8 + s8;
                    if (l == 0) {
                        const float* gp = g0p + (size_t)(k * C_ + s) * G_;
                        p0[s8] = gp[r]; p1[s8] = gp[128 + r];
                        p2[s8] = gp[256 + r]; p3[s8] = gp[384 + r];
                    } else {
                        const float* gp = rsl + ((size_t)(k & 3) * C_ + s) * G_;
                        p0[s8] = __hip_atomic_load(gp + r, __ATOMIC_RELAXED, __HIP_MEMORY_SCOPE_AGENT);
                        p1[s8] = __hip_atomic_load(gp + 128 + r, __ATOMIC_RELAXED, __HIP_MEMORY_SCOPE_AGENT);
                        p2[s8] = __hip_atomic_load(gp + 256 + r, __ATOMIC_RELAXED, __HIP_MEMORY_SCOPE_AGENT);
                        p3[s8] = __hip_atomic_load(gp + 384 + r, __ATOMIC_RELAXED, __HIP_MEMORY_SCOPE_AGENT);
                    }
                }
#pragma unroll
                for (int s8 = 0; s8 < 8; s8++) {
                    int s = half * 8 + s8;
                    int t = k * C_ + s;
                    const f4v* hb4 = (const f4v*)(hsh[t & 1] + q * 36);
                    f4v hv[8];
#pragma unroll
                    for (int j = 0; j < 8; j++) hv[j] = hb4[j];   // 8 ds_read_b128, shared by 4 dots
                    float zi, zf, zg, zo;
                    DOT32R(zi, w0, hv);
                    DOT32R(zf, w1, hv);
                    DOT32R(zg, w2, hv);
                    DOT32R(zo, w3, hv);
                    zi += __shfl_xor(zi, 1); zi += __shfl_xor(zi, 2);
                    zf += __shfl_xor(zf, 1); zf += __shfl_xor(zf, 2);
                    zg += __shfl_xor(zg, 1); zg += __shfl_xor(zg, 2);
                    zo += __shfl_xor(zo, 1); zo += __shfl_xor(zo, 2);
                    zi += p0[s8]; zf += p1[s8]; zg += p2[s8]; zo += p3[s8];
                    float ai = sigmoid_(zi), af = sigmoid_(zf);
                    float ag = tanh_(zg),    ao = sigmoid_(zo);
                    c = fmaf(af, c, ai * ag);
                    float hn = ao * tanh_(c);
                    if (q == 0) hsh[(t + 1) & 1][HOFF(r)] = hn;
                    hreg[s] = hn;
                    __syncthreads();
                }
            }
            // chunk end: write h once (keeps vmem out of the step loop)
            if (q == 0) {
#pragma unroll
                for (int s = 0; s < C_; s++)
                    __hip_atomic_store(hob + (size_t)(k * C_ + s) * 128 + r, hreg[s],
                                       __ATOMIC_RELAXED, __HIP_MEMORY_SCOPE_AGENT);
            }
            __syncthreads();   // implicit vmcnt(0): h stores drained before publish
            if (tid == 0) __hip_atomic_store(fh, k + 1, __ATOMIC_RELEASE, __HIP_MEMORY_SCOPE_AGENT);
        }
    } else {
        // ======== xproj producer (layers 1..3) ========
        const int li = (wg - 64) >> 4;     // 0..2
        const int l = li + 1, b = (wg - 64) & 15;
        __shared__ __align__(16) float hch[C_][HROW_];
        f4v w0[8], w1[8], w2[8], w3[8];
        const float* wl = Wih + (size_t)l * G_ * 128;
        LOAD_W8(w0, wl + ((size_t)(0 * 128 + r)) * 128 + q * 32);
        LOAD_W8(w1, wl + ((size_t)(1 * 128 + r)) * 128 + q * 32);
        LOAD_W8(w2, wl + ((size_t)(2 * 128 + r)) * 128 + q * 32);
        LOAD_W8(w3, wl + ((size_t)(3 * 128 + r)) * 128 + q * 32);
        float bs0 = bih[l * G_ + r] + bhh[l * G_ + r];
        float bs1 = bih[l * G_ + 128 + r] + bhh[l * G_ + 128 + r];
        float bs2 = bih[l * G_ + 256 + r] + bhh[l * G_ + 256 + r];
        float bs3 = bih[l * G_ + 384 + r] + bhh[l * G_ + 384 + r];
        const float* hsrc = h_glob + ((size_t)(l - 1) * 16 + b) * T_ * 128;
        float* rout = ring + ((size_t)li * 16 + b) * (4 * C_ * G_);
        int* fhp = flag_h + (l - 1) * 16 + b;   // upstream rec progress (data)
        int* fhme = flag_h + l * 16 + b;        // our rec progress (backpressure)
        int* fgo = flag_g + li * 16 + b;

        for (int k = 0; k < NCHUNK_; k++) {
            if (tid == 0) {
                wait_ge_(fhp, k + 1);
                if (k >= 4) wait_ge_(fhme, k - 3);
            }
            __syncthreads();   // wait done + previous chunk's hch reads complete
            {   // stage C_*128 = 2048 h values (4 per thread) into padded layout
#pragma unroll
                for (int i = 0; i < 4; i++) {
                    int idx = i * 512 + tid;
                    hch[idx >> 7][HOFF(idx & 127)] =
                        __hip_atomic_load(hsrc + (size_t)k * C_ * 128 + idx,
                                          __ATOMIC_RELAXED, __HIP_MEMORY_SCOPE_AGENT);
                }
            }
            __syncthreads();
#pragma unroll
            for (int s = 0; s < C_; s++) {
                const f4v* hb4 = (const f4v*)(hch[s] + q * 36);
                f4v hv[8];
#pragma unroll
                for (int j = 0; j < 8; j++) hv[j] = hb4[j];
                float z0, z1, z2, z3;
                DOT32R(z0, w0, hv);
                DOT32R(z1, w1, hv);
                DOT32R(z2, w2, hv);
                DOT32R(z3, w3, hv);
                z0 += __shfl_xor(z0, 1); z0 += __shfl_xor(z0, 2);
                z1 += __shfl_xor(z1, 1); z1 += __shfl_xor(z1, 2);
                z2 += __shfl_xor(z2, 1); z2 += __shfl_xor(z2, 2);
                z3 += __shfl_xor(z3, 1); z3 += __shfl_xor(z3, 2);
                if (q == 0) {
                    float* ro = rout + ((size_t)(k & 3) * C_ + s) * G_;
                    __hip_atomic_store(ro + r, z0 + bs0, __ATOMIC_RELAXED, __HIP_MEMORY_SCOPE_AGENT);
                    __hip_atomic_store(ro + 128 + r, z1 + bs1, __ATOMIC_RELAXED, __HIP_MEMORY_SCOPE_AGENT);
                    __hip_atomic_store(ro + 256 + r, z2 + bs2, __ATOMIC_RELAXED, __HIP_MEMORY_SCOPE_AGENT);
                    __hip_atomic_store(ro + 384 + r, z3 + bs3, __ATOMIC_RELAXED, __HIP_MEMORY_SCOPE_AGENT);
                }
            }
            __syncthreads();   // drains vmcnt: ring chunk in L2 before publish
            if (tid == 0) __hip_atomic_store(fgo, k + 1, __ATOMIC_RELEASE, __HIP_MEMORY_SCOPE_AGENT);
        }
    }
}

// ---------------- InstanceNorm stats (h3 only) ----------------
__global__ __launch_bounds__(512) void in_stats(const float* __restrict__ in,
                                                float* __restrict__ mu,
                                                float* __restrict__ inv) {
    int b = blockIdx.x;
    int tid = threadIdx.x;
    int h = tid & 127, r = tid >> 7;
    const float* ib = in + (size_t)b * T_ * H_;
    float s = 0.f, q = 0.f;
    for (int t = r; t < T_; t += 4) { float v = ib[t * H_ + h]; s += v; q += v * v; }
    __shared__ float ls[512], lq[512];
    ls[tid] = s; lq[tid] = q;
    __syncthreads();
    if (r == 0) {
        s = ls[h] + ls[h + 128] + ls[h + 256] + ls[h + 384];
        q = lq[h] + lq[h + 128] + lq[h + 256] + lq[h + 384];
        float m = s * (1.f / T_);
        float v = q * (1.f / T_) - m * m;
        mu[b * 128 + h] = m;
        inv[b * 128 + h] = rsqrtf(fmaxf(v, 0.f) + EPS_);
    }
}

// ---------------- mega-tail: px-IN stats + scores + softmax + att map + classify ----
// One WG (256 thr) per batch b.
__global__ __launch_bounds__(256) void mega_tail(const float* __restrict__ ph,
                                                 const float* __restrict__ px,
                                                 const float* __restrict__ attn_w,
                                                 const float* __restrict__ fc_w,
                                                 const float* __restrict__ fc_b,
                                                 float* __restrict__ out,
                                                 float* __restrict__ out_att) {
    int b = blockIdx.x;
    int tid = threadIdx.x;
    int h = tid & 127, st = tid >> 7;          // 2 t-stripes
    int wv = tid >> 6, ln = tid & 63;          // 4 waves
    const float* pxb = px + (size_t)b * T_ * H_;
    const float* phb = ph + (size_t)b * T_ * H_;
    __shared__ float muS[128], invS[128];
    __shared__ float ls[256], lq[256];
    __shared__ float lsc[256], tmp[256], wsh[256];

    // phase 1: px InstanceNorm stats over T
    {
        float s = 0.f, q = 0.f;
        for (int t = st; t < T_; t += 2) { float v = pxb[t * 128 + h]; s += v; q += v * v; }
        ls[tid] = s; lq[tid] = q;
        __syncthreads();
        if (st == 0) {
            s = ls[h] + ls[h + 128]; q = lq[h] + lq[h + 128];
            float m = s * (1.f / T_);
            float v = q * (1.f / T_) - m * m;
            muS[h] = m;
            invS[h] = rsqrtf(fmaxf(v, 0.f) + EPS_);
        }
        __syncthreads();
    }
    // phase 2: scores l[t] = sum_h tanh(ph + IN(px)) * attn_w  (one wave per t)
    for (int t4 = 0; t4 < T_; t4 += 4) {
        int t = t4 + wv;
        float v0 = phb[t * 128 + ln] + (pxb[t * 128 + ln] - muS[ln]) * invS[ln];
        float v1 = phb[t * 128 + 64 + ln] + (pxb[t * 128 + 64 + ln] - muS[64 + ln]) * invS[64 + ln];
        float sv = tanh_(v0) * attn_w[ln] + tanh_(v1) * attn_w[64 + ln];
#pragma unroll
        for (int off = 32; off > 0; off >>= 1) sv += __shfl_down(sv, off);
        if (ln == 0) lsc[t] = sv;
    }
    __syncthreads();
    // phase 3: softmax over t
    {
        float v = lsc[tid];
        tmp[tid] = v; __syncthreads();
        for (int off = 128; off > 0; off >>= 1) { if (tid < off) tmp[tid] = fmaxf(tmp[tid], tmp[tid + off]); __syncthreads(); }
        float mx = tmp[0]; __syncthreads();
        float e = __expf(v - mx);
        tmp[tid] = e; __syncthreads();
        for (int off = 128; off > 0; off >>= 1) { if (tid < off) tmp[tid] += tmp[tid + off]; __syncthreads(); }
        wsh[tid] = e / tmp[0];
        __syncthreads();
    }
    // phase 4: attention map (value constant across d; alpha = softmax_t / D)
    {
        float* ob = out_att + (size_t)b * T_ * D_;
        const float invD = 1.f / (float)D_;
        for (int i = tid; i < T_ * D_; i += 256) ob[i] = wsh[i >> 7] * invD;
    }
    // phase 5: context + FC
    {
        float acc = 0.f;
        for (int t = st; t < T_; t += 2) acc = fmaf(phb[t * 128 + h], wsh[t], acc);
        ls[tid] = acc;
        __syncthreads();
        if (tid < 128) ls[tid] = ls[tid] + ls[tid + 128];
        __syncthreads();
        if (tid < NC_) {
            float s = fc_b[tid];
            const float* fw = fc_w + tid * 128;
            for (int k = 0; k < 128; k++) s = fmaf(ls[k], fw[k], s);
            out[b * NC_ + tid] = s;
        }
    }
}

// ---------------- launcher ----------------
extern "C" void kernel_launch(void* const* d_in, const int* in_sizes, int n_in,
                              void* d_out, int out_size, void* d_ws, size_t ws_size,
                              hipStream_t stream) {
    const float* x        = (const float*)d_in[0];
    const float* Wih      = (const float*)d_in[1];
    const float* Whh      = (const float*)d_in[2];
    const float* bih      = (const float*)d_in[3];
    const float* bhh      = (const float*)d_in[4];
    const float* proj_h_w = (const float*)d_in[5];
    const float* proj_h_b = (const float*)d_in[6];
    const float* proj_x_w = (const float*)d_in[7];
    const float* proj_x_b = (const float*)d_in[8];
    const float* attn_w   = (const float*)d_in[9];
    const float* fc_w     = (const float*)d_in[10];
    const float* fc_b     = (const float*)d_in[11];
    float* out = (float*)d_out;

    float* ws = (float*)d_ws;
    const size_t NTD = (size_t)B_ * T_ * D_;       // 524288
    float* xnorm  = ws;                            // NTD
    float* h_glob = xnorm + NTD;                   // 4*NTD
    float* g0     = h_glob + 4 * NTD;              // B*T*G = 4*NTD
    float* ring   = g0 + 4 * NTD;                  // 3*16*4*C_*G
    float* smalls = ring + (size_t)3 * 16 * 4 * C_ * G_;
    float* sum_bd = smalls;
    float* sq_bd  = sum_bd + 2048;
    float* sdv    = sq_bd + 2048;
    float* mu_ln  = sdv + 128;
    float* inv_ln = mu_ln + 2048;
    int*   flags  = (int*)(inv_ln + 2048);
    int*   flag_h = flags;                         // [64]
    int*   flag_g = flags + 64;                    // [48]
    // post-scan reuse (dispatch-boundary ordering):
    float* ph    = h_glob;                         // layer-0/1 h dead after scan
    float* px    = h_glob + NTD;
    const float* h3 = h_glob + 3 * NTD;

    hipMemsetAsync((void*)flags, 0, 128 * sizeof(int), stream);

    // input normalize
    stats_bd<<<16, 512, 0, stream>>>(x, sum_bd, sq_bd);
    stats_d<<<1, 128, 0, stream>>>(sum_bd, sq_bd, sdv);
    normalize_x<<<2048, 256, 0, stream>>>(x, sum_bd, sq_bd, sdv, xnorm);

    // layer-0 input projection (time-parallel GEMM), then chunk-pipelined stack
    dim3 g1(64, 8);
    gemm_bias_k128<<<g1, 256, 0, stream>>>(xnorm, Wih, bih, bhh, g0, G_);
    scan_pipe4<<<112, 512, 0, stream>>>(g0, Wih, Whh, bih, bhh,
                                        h_glob, ring, flag_h, flag_g);

    // post-LSTM: IN stats on h3; ph = IN(h3) @ W^T + b fused; px = xnorm @ W^T + b
    in_stats<<<16, 512, 0, stream>>>(h3, mu_ln, inv_ln);
    dim3 g2(64, 2);
    gemm_norm_k128<<<g2, 256, 0, stream>>>(h3, mu_ln, inv_ln, proj_h_w, proj_h_b, ph, H_);
    gemm_bias_k128<<<g2, 256, 0, stream>>>(xnorm, proj_x_w, proj_x_b, nullptr, px, H_);

    // fused tail: px-IN stats + scores + softmax + attention map + classify
    mega_tail<<<16, 256, 0, stream>>>(ph, px, attn_w, fc_w, fc_b, out, out + B_ * NC_);
}

// Round 12
// 497.790 us; speedup vs baseline: 1.1296x; 1.1296x over previous
//
#include <hip/hip_runtime.h>
#include <math.h>
#include <cstddef>

#define B_ 16
#define T_ 256
#define D_ 128
#define H_ 128
#define L_ 4
#define G_ 512          // 4*H
#define NC_ 10
#define EPS_ 1e-5f
#define C_ 16           // pipeline chunk (timesteps per flag)
#define NCHUNK_ (T_ / C_)

// padded LDS row: +4 floats per 32 -> 144-float rows; quarter q at q*36 floats
#define HROW_ 144
#define HOFF(k) ((k) + (((k) >> 5) << 2))

typedef float f4v __attribute__((ext_vector_type(4)));

// 8 x global_load_dwordx4 -> 32 floats resident (compiler cannot remat asm)
#define LOAD_W8(w, base)                                                   \
    asm volatile(                                                          \
        "global_load_dwordx4 %0, %8, off\n\t"                             \
        "global_load_dwordx4 %1, %8, off offset:16\n\t"                   \
        "global_load_dwordx4 %2, %8, off offset:32\n\t"                   \
        "global_load_dwordx4 %3, %8, off offset:48\n\t"                   \
        "global_load_dwordx4 %4, %8, off offset:64\n\t"                   \
        "global_load_dwordx4 %5, %8, off offset:80\n\t"                   \
        "global_load_dwordx4 %6, %8, off offset:96\n\t"                   \
        "global_load_dwordx4 %7, %8, off offset:112\n\t"                  \
        "s_waitcnt vmcnt(0)"                                               \
        : "=&v"(w[0]), "=&v"(w[1]), "=&v"(w[2]), "=&v"(w[3]),              \
          "=&v"(w[4]), "=&v"(w[5]), "=&v"(w[6]), "=&v"(w[7])               \
        : "v"(base)                                                        \
        : "memory")

// 32-k partial dot against pre-loaded h registers (params avoid x/y/z/w tokens)
#define DOT32R(dst_, warr_, hvarr_)                                        \
    {                                                                      \
        float d0_ = 0.f, d1_ = 0.f;                                        \
        _Pragma("unroll")                                                  \
        for (int j_ = 0; j_ < 8; j_++) {                                   \
            d0_ = fmaf(warr_[j_].x, hvarr_[j_].x, d0_);                    \
            d1_ = fmaf(warr_[j_].y, hvarr_[j_].y, d1_);                    \
            d0_ = fmaf(warr_[j_].z, hvarr_[j_].z, d0_);                    \
            d1_ = fmaf(warr_[j_].w, hvarr_[j_].w, d1_);                    \
        }                                                                  \
        dst_ = d0_ + d1_;                                                  \
    }

// ---------------- device helpers ----------------
__device__ __forceinline__ float sigmoid_(float x) {
    x = fminf(fmaxf(x, -30.f), 30.f);
    return 1.f / (1.f + __expf(-x));
}
__device__ __forceinline__ float tanh_(float x) {
    float ax = fminf(fabsf(x), 15.f);
    float e = __expf(2.f * ax);
    float t = 1.f - 2.f / (e + 1.f);
    return copysignf(t, x);
}
__device__ __forceinline__ void wait_ge_(int* p, int v) {
    if (__hip_atomic_load(p, __ATOMIC_RELAXED, __HIP_MEMORY_SCOPE_AGENT) < v) {
        do { __builtin_amdgcn_s_sleep(1); }
        while (__hip_atomic_load(p, __ATOMIC_RELAXED, __HIP_MEMORY_SCOPE_AGENT) < v);
    }
    (void)__hip_atomic_load(p, __ATOMIC_ACQUIRE, __HIP_MEMORY_SCOPE_AGENT);
}

// ---------------- head: per-(b,d) raw stats over T ----------------
__global__ __launch_bounds__(512) void stats_bd(const float* __restrict__ x,
                                                float* __restrict__ sum_bd,
                                                float* __restrict__ sq_bd) {
    int b = blockIdx.x;
    int tid = threadIdx.x;
    int d = tid & 127, r = tid >> 7;
    const float* xb = x + (size_t)b * T_ * D_;
    float s = 0.f, q = 0.f;
    for (int t = r; t < T_; t += 4) {
        float v = xb[t * D_ + d];
        s += v; q += v * v;
    }
    __shared__ float ls[512], lq[512];
    ls[tid] = s; lq[tid] = q;
    __syncthreads();
    if (r == 0) {
        s = ls[d] + ls[d + 128] + ls[d + 256] + ls[d + 384];
        q = lq[d] + lq[d + 128] + lq[d + 256] + lq[d + 384];
        sum_bd[b * 128 + d] = s;
        sq_bd[b * 128 + d] = q;
    }
}

// fused factors: xn[b,t,d] = (x - mu_bd) * invn  (global detached norm + IN)
__global__ __launch_bounds__(128) void stats_norm(const float* __restrict__ sum_bd,
                                                  const float* __restrict__ sq_bd,
                                                  float* __restrict__ mu_bd,
                                                  float* __restrict__ invn) {
    int d = threadIdx.x;
    float s = 0.f, q = 0.f;
    for (int b = 0; b < B_; b++) { s += sum_bd[b * 128 + d]; q += sq_bd[b * 128 + d]; }
    float n = (float)(B_ * T_);
    float m = s / n;
    float varu = (q - n * m * m) / (n - 1.f);
    float sd = sqrtf(fmaxf(varu, 0.f)) + EPS_;
    for (int b = 0; b < B_; b++) {
        float mu = sum_bd[b * 128 + d] * (1.f / T_);
        float varT = sq_bd[b * 128 + d] * (1.f / T_) - mu * mu;
        mu_bd[b * 128 + d] = mu;
        invn[b * 128 + d] = rsqrtf(fmaxf(varT, 0.f) + EPS_ * sd * sd);
    }
}

// ---------------- K=128 GEMM, A normalized on load; b2 nullable ----------------
__global__ __launch_bounds__(256) void gemm_norm_k128(const float* __restrict__ A,
                                                      const float* __restrict__ mu,
                                                      const float* __restrict__ inv,
                                                      const float* __restrict__ Bw,
                                                      const float* __restrict__ b1,
                                                      const float* __restrict__ b2,
                                                      float* __restrict__ C, int N) {
    __shared__ __align__(16) float As[16][64];
    __shared__ __align__(16) float Bs[16][64];
    int tid = threadIdx.x;
    int m0 = blockIdx.x * 64, n0 = blockIdx.y * 64;
    int lr = tid >> 2;
    int lc = (tid & 3) << 2;
    int tm = (tid >> 4) << 2;
    int tn = (tid & 15) << 2;
    float acc[4][4] = {};
    int bidx = (m0 + lr) >> 8;
    const float* Arow = A + (size_t)(m0 + lr) * 128 + lc;
    const float* Brow = Bw + (size_t)(n0 + lr) * 128 + lc;
    const float* mup = mu + bidx * 128 + lc;
    const float* ivp = inv + bidx * 128 + lc;
    for (int kb = 0; kb < 128; kb += 16) {
        float4 av = *(const float4*)(Arow + kb);
        float4 m4 = *(const float4*)(mup + kb);
        float4 i4 = *(const float4*)(ivp + kb);
        av.x = (av.x - m4.x) * i4.x; av.y = (av.y - m4.y) * i4.y;
        av.z = (av.z - m4.z) * i4.z; av.w = (av.w - m4.w) * i4.w;
        float4 bv = *(const float4*)(Brow + kb);
        __syncthreads();
        As[lc + 0][lr] = av.x; As[lc + 1][lr] = av.y; As[lc + 2][lr] = av.z; As[lc + 3][lr] = av.w;
        Bs[lc + 0][lr] = bv.x; Bs[lc + 1][lr] = bv.y; Bs[lc + 2][lr] = bv.z; Bs[lc + 3][lr] = bv.w;
        __syncthreads();
#pragma unroll
        for (int k = 0; k < 16; k++) {
            float4 a4 = *(const float4*)&As[k][tm];
            float4 b4 = *(const float4*)&Bs[k][tn];
            float ar[4] = {a4.x, a4.y, a4.z, a4.w};
            float br[4] = {b4.x, b4.y, b4.z, b4.w};
#pragma unroll
            for (int i = 0; i < 4; i++)
#pragma unroll
                for (int j = 0; j < 4; j++)
                    acc[i][j] = fmaf(ar[i], br[j], acc[i][j]);
        }
    }
#pragma unroll
    for (int i = 0; i < 4; i++) {
        int row = m0 + tm + i;
#pragma unroll
        for (int j = 0; j < 4; j++) {
            int col = n0 + tn + j;
            float bias = b1[col] + (b2 ? b2[col] : 0.f);
            C[(size_t)row * N + col] = acc[i][j] + bias;
        }
    }
}

// ---------------- scan + hidden riders ----------------
// 144 WGs x 512 thr:
//   wg[0..63]    rec(l,b)          (unchanged from R10)
//   wg[64..111]  xproj(l=1..3,b)   (unchanged from R10)
//   wg[112..127] px rider: px[b] = norm(x[b]) @ proj_x_w^T + b, + px IN stats
//   wg[128..143] h3-stats rider: IN stats of layer-3 h, chunk-incremental
__global__ __attribute__((amdgpu_waves_per_eu(2, 2))) __launch_bounds__(512)
void scan_pipe5(const float* __restrict__ g0,
                const float* __restrict__ x,
                const float* __restrict__ Wih, const float* __restrict__ Whh,
                const float* __restrict__ bih, const float* __restrict__ bhh,
                const float* __restrict__ proj_x_w, const float* __restrict__ proj_x_b,
                const float* __restrict__ mu_bd, const float* __restrict__ invn,
                float* __restrict__ h_glob,        // [L][B][T][H]
                float* __restrict__ ring,          // [3][B][4][C_][G]
                float* __restrict__ px,            // [B][T][H]
                float* __restrict__ mu_px, float* __restrict__ inv_px,
                float* __restrict__ mu_ln, float* __restrict__ inv_ln,
                int* __restrict__ flag_h,          // [L][B]
                int* __restrict__ flag_g) {        // [3][B]
    const int wg = blockIdx.x;
    const int tid = threadIdx.x;
    __shared__ __align__(16) float shbuf[16 * HROW_];   // 9216 B, shared by all roles

    if (wg < 64) {
        // ======== recurrent consumer (l, b) ========
        const int r = tid >> 2, q = tid & 3;
        const int l = wg >> 4, b = wg & 15;
        f4v w0[8], w1[8], w2[8], w3[8];
        const float* wl = Whh + (size_t)l * G_ * 128;
        LOAD_W8(w0, wl + ((size_t)(0 * 128 + r)) * 128 + q * 32);
        LOAD_W8(w1, wl + ((size_t)(1 * 128 + r)) * 128 + q * 32);
        LOAD_W8(w2, wl + ((size_t)(2 * 128 + r)) * 128 + q * 32);
        LOAD_W8(w3, wl + ((size_t)(3 * 128 + r)) * 128 + q * 32);
        float c = 0.f;
        if (tid < HROW_) shbuf[tid] = 0.f;               // h buffer 0
        const float* g0p = g0 + (size_t)b * T_ * G_;
        const float* rsl = (l > 0) ? ring + ((size_t)(l - 1) * 16 + b) * (4 * C_ * G_) : ring;
        float* hob = h_glob + ((size_t)l * 16 + b) * T_ * 128;
        int* fg = (l > 0) ? flag_g + (l - 1) * 16 + b : flag_g;
        int* fh = flag_h + l * 16 + b;
        float hreg[C_];
        __syncthreads();

        for (int k = 0; k < NCHUNK_; k++) {
            if (l > 0) {
                if (tid == 0) wait_ge_(fg, k + 1);
                __syncthreads();
            }
#pragma unroll
            for (int half = 0; half < 2; half++) {
                float p0[8], p1[8], p2[8], p3[8];
#pragma unroll
                for (int s8 = 0; s8 < 8; s8++) {
                    int s = half * 8 + s8;
                    if (l == 0) {
                        const float* gp = g0p + (size_t)(k * C_ + s) * G_;
                        p0[s8] = gp[r]; p1[s8] = gp[128 + r];
                        p2[s8] = gp[256 + r]; p3[s8] = gp[384 + r];
                    } else {
                        const float* gp = rsl + ((size_t)(k & 3) * C_ + s) * G_;
                        p0[s8] = __hip_atomic_load(gp + r, __ATOMIC_RELAXED, __HIP_MEMORY_SCOPE_AGENT);
                        p1[s8] = __hip_atomic_load(gp + 128 + r, __ATOMIC_RELAXED, __HIP_MEMORY_SCOPE_AGENT);
                        p2[s8] = __hip_atomic_load(gp + 256 + r, __ATOMIC_RELAXED, __HIP_MEMORY_SCOPE_AGENT);
                        p3[s8] = __hip_atomic_load(gp + 384 + r, __ATOMIC_RELAXED, __HIP_MEMORY_SCOPE_AGENT);
                    }
                }
#pragma unroll
                for (int s8 = 0; s8 < 8; s8++) {
                    int s = half * 8 + s8;
                    int t = k * C_ + s;
                    const f4v* hb4 = (const f4v*)(shbuf + (t & 1) * HROW_ + q * 36);
                    f4v hv[8];
#pragma unroll
                    for (int j = 0; j < 8; j++) hv[j] = hb4[j];
                    float zi, zf, zg, zo;
                    DOT32R(zi, w0, hv);
                    DOT32R(zf, w1, hv);
                    DOT32R(zg, w2, hv);
                    DOT32R(zo, w3, hv);
                    zi += __shfl_xor(zi, 1); zi += __shfl_xor(zi, 2);
                    zf += __shfl_xor(zf, 1); zf += __shfl_xor(zf, 2);
                    zg += __shfl_xor(zg, 1); zg += __shfl_xor(zg, 2);
                    zo += __shfl_xor(zo, 1); zo += __shfl_xor(zo, 2);
                    zi += p0[s8]; zf += p1[s8]; zg += p2[s8]; zo += p3[s8];
                    float ai = sigmoid_(zi), af = sigmoid_(zf);
                    float ag = tanh_(zg),    ao = sigmoid_(zo);
                    c = fmaf(af, c, ai * ag);
                    float hn = ao * tanh_(c);
                    if (q == 0) shbuf[((t + 1) & 1) * HROW_ + HOFF(r)] = hn;
                    hreg[s] = hn;
                    __syncthreads();
                }
            }
            if (q == 0) {
#pragma unroll
                for (int s = 0; s < C_; s++)
                    __hip_atomic_store(hob + (size_t)(k * C_ + s) * 128 + r, hreg[s],
                                       __ATOMIC_RELAXED, __HIP_MEMORY_SCOPE_AGENT);
            }
            __syncthreads();
            if (tid == 0) __hip_atomic_store(fh, k + 1, __ATOMIC_RELEASE, __HIP_MEMORY_SCOPE_AGENT);
        }
    } else if (wg < 112) {
        // ======== xproj producer (layers 1..3) ========
        const int r = tid >> 2, q = tid & 3;
        const int li = (wg - 64) >> 4;
        const int l = li + 1, b = (wg - 64) & 15;
        f4v w0[8], w1[8], w2[8], w3[8];
        const float* wl = Wih + (size_t)l * G_ * 128;
        LOAD_W8(w0, wl + ((size_t)(0 * 128 + r)) * 128 + q * 32);
        LOAD_W8(w1, wl + ((size_t)(1 * 128 + r)) * 128 + q * 32);
        LOAD_W8(w2, wl + ((size_t)(2 * 128 + r)) * 128 + q * 32);
        LOAD_W8(w3, wl + ((size_t)(3 * 128 + r)) * 128 + q * 32);
        float bs0 = bih[l * G_ + r] + bhh[l * G_ + r];
        float bs1 = bih[l * G_ + 128 + r] + bhh[l * G_ + 128 + r];
        float bs2 = bih[l * G_ + 256 + r] + bhh[l * G_ + 256 + r];
        float bs3 = bih[l * G_ + 384 + r] + bhh[l * G_ + 384 + r];
        const float* hsrc = h_glob + ((size_t)(l - 1) * 16 + b) * T_ * 128;
        float* rout = ring + ((size_t)li * 16 + b) * (4 * C_ * G_);
        int* fhp = flag_h + (l - 1) * 16 + b;
        int* fhme = flag_h + l * 16 + b;
        int* fgo = flag_g + li * 16 + b;

        for (int k = 0; k < NCHUNK_; k++) {
            if (tid == 0) {
                wait_ge_(fhp, k + 1);
                if (k >= 4) wait_ge_(fhme, k - 3);
            }
            __syncthreads();
#pragma unroll
            for (int i = 0; i < 4; i++) {
                int idx = i * 512 + tid;
                shbuf[(idx >> 7) * HROW_ + HOFF(idx & 127)] =
                    __hip_atomic_load(hsrc + (size_t)k * C_ * 128 + idx,
                                      __ATOMIC_RELAXED, __HIP_MEMORY_SCOPE_AGENT);
            }
            __syncthreads();
#pragma unroll
            for (int s = 0; s < C_; s++) {
                const f4v* hb4 = (const f4v*)(shbuf + s * HROW_ + q * 36);
                f4v hv[8];
#pragma unroll
                for (int j = 0; j < 8; j++) hv[j] = hb4[j];
                float z0, z1, z2, z3;
                DOT32R(z0, w0, hv);
                DOT32R(z1, w1, hv);
                DOT32R(z2, w2, hv);
                DOT32R(z3, w3, hv);
                z0 += __shfl_xor(z0, 1); z0 += __shfl_xor(z0, 2);
                z1 += __shfl_xor(z1, 1); z1 += __shfl_xor(z1, 2);
                z2 += __shfl_xor(z2, 1); z2 += __shfl_xor(z2, 2);
                z3 += __shfl_xor(z3, 1); z3 += __shfl_xor(z3, 2);
                if (q == 0) {
                    float* ro = rout + ((size_t)(k & 3) * C_ + s) * G_;
                    __hip_atomic_store(ro + r, z0 + bs0, __ATOMIC_RELAXED, __HIP_MEMORY_SCOPE_AGENT);
                    __hip_atomic_store(ro + 128 + r, z1 + bs1, __ATOMIC_RELAXED, __HIP_MEMORY_SCOPE_AGENT);
                    __hip_atomic_store(ro + 256 + r, z2 + bs2, __ATOMIC_RELAXED, __HIP_MEMORY_SCOPE_AGENT);
                    __hip_atomic_store(ro + 384 + r, z3 + bs3, __ATOMIC_RELAXED, __HIP_MEMORY_SCOPE_AGENT);
                }
            }
            __syncthreads();
            if (tid == 0) __hip_atomic_store(fgo, k + 1, __ATOMIC_RELEASE, __HIP_MEMORY_SCOPE_AGENT);
        }
    } else if (wg < 128) {
        // ======== px rider: px[b] = norm(x[b]) @ proj_x_w^T + b; + IN stats ========
        const int b = wg - 112;
        const int h = tid & 127, tq = tid >> 7;     // 4 t-strips per 16-t block
        f4v w0[8], w1[8], w2[8], w3[8];
        LOAD_W8(w0, proj_x_w + (size_t)h * 128 + 0);
        LOAD_W8(w1, proj_x_w + (size_t)h * 128 + 32);
        LOAD_W8(w2, proj_x_w + (size_t)h * 128 + 64);
        LOAD_W8(w3, proj_x_w + (size_t)h * 128 + 96);
        float bsx = proj_x_b[h];
        float muk = mu_bd[b * 128 + h], ivk = invn[b * 128 + h];   // staging role k == h
        const float* xb = x + (size_t)b * T_ * 128;
        float* pxb = px + (size_t)b * T_ * 128;
        float sacc = 0.f, qacc = 0.f;

        for (int blk = 0; blk < 16; blk++) {
            int t0 = blk * 16;
            __syncthreads();
#pragma unroll
            for (int j = 0; j < 4; j++) {
                int tt = tq * 4 + j;
                float v = xb[(size_t)(t0 + tt) * 128 + h];
                shbuf[tt * HROW_ + HOFF(h)] = (v - muk) * ivk;
            }
            __syncthreads();
#pragma unroll
            for (int j = 0; j < 4; j++) {
                int tt = tq * 4 + j;
                const float* row = shbuf + tt * HROW_;
                f4v hv[8];
                float p0, p1, p2, p3;
                const f4v* r4 = (const f4v*)(row + 0 * 36);
#pragma unroll
                for (int u = 0; u < 8; u++) hv[u] = r4[u];
                DOT32R(p0, w0, hv);
                r4 = (const f4v*)(row + 1 * 36);
#pragma unroll
                for (int u = 0; u < 8; u++) hv[u] = r4[u];
                DOT32R(p1, w1, hv);
                r4 = (const f4v*)(row + 2 * 36);
#pragma unroll
                for (int u = 0; u < 8; u++) hv[u] = r4[u];
                DOT32R(p2, w2, hv);
                r4 = (const f4v*)(row + 3 * 36);
#pragma unroll
                for (int u = 0; u < 8; u++) hv[u] = r4[u];
                DOT32R(p3, w3, hv);
                float val = (p0 + p1) + (p2 + p3) + bsx;
                pxb[(size_t)(t0 + tt) * 128 + h] = val;
                sacc += val; qacc += val * val;
            }
        }
        __syncthreads();
        shbuf[tq * 128 + h] = sacc;
        shbuf[512 + tq * 128 + h] = qacc;
        __syncthreads();
        if (tq == 0) {
            float s = shbuf[h] + shbuf[128 + h] + shbuf[256 + h] + shbuf[384 + h];
            float qq = shbuf[512 + h] + shbuf[640 + h] + shbuf[768 + h] + shbuf[896 + h];
            float m = s * (1.f / T_);
            float v = qq * (1.f / T_) - m * m;
            mu_px[b * 128 + h] = m;
            inv_px[b * 128 + h] = rsqrtf(fmaxf(v, 0.f) + EPS_);
        }
    } else {
        // ======== h3-stats rider: IN stats of layer-3 h, chunk-incremental ========
        const int b = wg - 128;
        const int h = tid & 127, st = tid >> 7;
        const float* hsrc = h_glob + ((size_t)3 * 16 + b) * T_ * 128;
        int* f3 = flag_h + 3 * 16 + b;
        float s = 0.f, q = 0.f;
        for (int k = 0; k < NCHUNK_; k++) {
            if (tid == 0) wait_ge_(f3, k + 1);
            __syncthreads();
#pragma unroll
            for (int j = 0; j < 4; j++) {
                int tt = st * 4 + j;
                float v = __hip_atomic_load(hsrc + (size_t)(k * C_ + tt) * 128 + h,
                                            __ATOMIC_RELAXED, __HIP_MEMORY_SCOPE_AGENT);
                s += v; q += v * v;
            }
        }
        shbuf[st * 128 + h] = s;
        shbuf[512 + st * 128 + h] = q;
        __syncthreads();
        if (st == 0) {
            float ss = shbuf[h] + shbuf[128 + h] + shbuf[256 + h] + shbuf[384 + h];
            float qq = shbuf[512 + h] + shbuf[640 + h] + shbuf[768 + h] + shbuf[896 + h];
            float m = ss * (1.f / T_);
            float v = qq * (1.f / T_) - m * m;
            mu_ln[b * 128 + h] = m;
            inv_ln[b * 128 + h] = rsqrtf(fmaxf(v, 0.f) + EPS_);
        }
    }
}

// ---------------- attention score (parallel, 4096 blocks) ----------------
__global__ __launch_bounds__(128) void score_kernel(const float* __restrict__ ph,
                                                    const float* __restrict__ px,
                                                    const float* __restrict__ mu_px,
                                                    const float* __restrict__ inv_px,
                                                    const float* __restrict__ attn_w,
                                                    float* __restrict__ lsc) {
    int bt = blockIdx.x;
    int b = bt >> 8;
    int h = threadIdx.x;
    size_t o = (size_t)bt * 128 + h;
    float v = ph[o] + (px[o] - mu_px[b * 128 + h]) * inv_px[b * 128 + h];
    float sv = tanh_(v) * attn_w[h];
    __shared__ float red[128];
    red[h] = sv;
    __syncthreads();
    for (int off = 64; off > 0; off >>= 1) {
        if (h < off) red[h] += red[h + off];
        __syncthreads();
    }
    if (h == 0) lsc[bt] = red[0];
}

// ---------------- tail3: softmax + attention map + classify (16 WGs) ----------------
__global__ __launch_bounds__(256) void tail3(const float* __restrict__ lsc,
                                             const float* __restrict__ ph,
                                             const float* __restrict__ fc_w,
                                             const float* __restrict__ fc_b,
                                             float* __restrict__ out,
                                             float* __restrict__ out_att) {
    int b = blockIdx.x;
    int tid = threadIdx.x;
    int h = tid & 127, st = tid >> 7;
    const float* phb = ph + (size_t)b * T_ * H_;
    __shared__ float tmp[256], wsh[256], ls[256];
    float v = lsc[b * 256 + tid];
    tmp[tid] = v; __syncthreads();
    for (int off = 128; off > 0; off >>= 1) { if (tid < off) tmp[tid] = fmaxf(tmp[tid], tmp[tid + off]); __syncthreads(); }
    float mx = tmp[0]; __syncthreads();
    float e = __expf(v - mx);
    tmp[tid] = e; __syncthreads();
    for (int off = 128; off > 0; off >>= 1) { if (tid < off) tmp[tid] += tmp[tid + off]; __syncthreads(); }
    wsh[tid] = e / tmp[0];
    __syncthreads();
    {   // attention map: alpha = softmax_t / D, constant across d
        float* ob = out_att + (size_t)b * T_ * D_;
        const float invD = 1.f / (float)D_;
        for (int i = tid; i < T_ * D_; i += 256) ob[i] = wsh[i >> 7] * invD;
    }
    {   // context + FC
        float acc = 0.f;
        for (int t = st; t < T_; t += 2) acc = fmaf(phb[t * 128 + h], wsh[t], acc);
        ls[tid] = acc;
        __syncthreads();
        if (tid < 128) ls[tid] = ls[tid] + ls[tid + 128];
        __syncthreads();
        if (tid < NC_) {
            float s = fc_b[tid];
            const float* fw = fc_w + tid * 128;
            for (int k = 0; k < 128; k++) s = fmaf(ls[k], fw[k], s);
            out[b * NC_ + tid] = s;
        }
    }
}

// ---------------- launcher ----------------
extern "C" void kernel_launch(void* const* d_in, const int* in_sizes, int n_in,
                              void* d_out, int out_size, void* d_ws, size_t ws_size,
                              hipStream_t stream) {
    const float* x        = (const float*)d_in[0];
    const float* Wih      = (const float*)d_in[1];
    const float* Whh      = (const float*)d_in[2];
    const float* bih      = (const float*)d_in[3];
    const float* bhh      = (const float*)d_in[4];
    const float* proj_h_w = (const float*)d_in[5];
    const float* proj_h_b = (const float*)d_in[6];
    const float* proj_x_w = (const float*)d_in[7];
    const float* proj_x_b = (const float*)d_in[8];
    const float* attn_w   = (const float*)d_in[9];
    const float* fc_w     = (const float*)d_in[10];
    const float* fc_b     = (const float*)d_in[11];
    float* out = (float*)d_out;

    float* ws = (float*)d_ws;
    const size_t NTD = (size_t)B_ * T_ * D_;       // 524288
    float* h_glob = ws;                            // 4*NTD
    float* g0     = h_glob + 4 * NTD;              // 4*NTD
    float* ring   = g0 + 4 * NTD;                  // 3*NTD (3*16*4*16*512)
    float* px     = ring + 3 * NTD;                // 1*NTD
    float* smalls = px + NTD;
    float* sum_bd = smalls;
    float* sq_bd  = sum_bd + 2048;
    float* mu_bd  = sq_bd + 2048;
    float* invn   = mu_bd + 2048;
    float* mu_ln  = invn + 2048;
    float* inv_ln = mu_ln + 2048;
    float* mu_px  = inv_ln + 2048;
    float* inv_px = mu_px + 2048;
    float* lsc    = inv_px + 2048;
    int*   flags  = (int*)(lsc + 4096);
    int*   flag_h = flags;                         // [64]
    int*   flag_g = flags + 64;                    // [48]
    // post-scan reuse: ph takes layer-0 h area
    float* ph = h_glob;
    const float* h3 = h_glob + 3 * NTD;

    hipMemsetAsync((void*)flags, 0, 128 * sizeof(int), stream);

    // head: stats + fused-normalization factors + layer-0 input projection
    stats_bd<<<16, 512, 0, stream>>>(x, sum_bd, sq_bd);
    stats_norm<<<1, 128, 0, stream>>>(sum_bd, sq_bd, mu_bd, invn);
    dim3 g1(64, 8);
    gemm_norm_k128<<<g1, 256, 0, stream>>>(x, mu_bd, invn, Wih, bih, bhh, g0, G_);

    // scan + hidden riders (px projection + px stats + h3 stats)
    scan_pipe5<<<144, 512, 0, stream>>>(g0, x, Wih, Whh, bih, bhh,
                                        proj_x_w, proj_x_b, mu_bd, invn,
                                        h_glob, ring, px, mu_px, inv_px,
                                        mu_ln, inv_ln, flag_h, flag_g);

    // ph = IN(h3) @ proj_h_w^T + b (normalization fused)
    dim3 g2(64, 2);
    gemm_norm_k128<<<g2, 256, 0, stream>>>(h3, mu_ln, inv_ln, proj_h_w, proj_h_b,
                                           nullptr, ph, H_);

    // attention + classify
    score_kernel<<<4096, 128, 0, stream>>>(ph, px, mu_px, inv_px, attn_w, lsc);
    tail3<<<16, 256, 0, stream>>>(lsc, ph, fc_w, fc_b, out, out + B_ * NC_);
}

// Round 13
// 493.265 us; speedup vs baseline: 1.1400x; 1.0092x over previous
//
#include <hip/hip_runtime.h>
#include <math.h>
#include <cstddef>

#define B_ 16
#define T_ 256
#define D_ 128
#define H_ 128
#define L_ 4
#define G_ 512          // 4*H
#define NC_ 10
#define EPS_ 1e-5f
#define C_ 16           // pipeline chunk (timesteps per flag)
#define NCHUNK_ (T_ / C_)

// padded LDS row: +4 floats per 32 -> 144-float rows; quarter q at q*36 floats
#define HROW_ 144
#define HOFF(k) ((k) + (((k) >> 5) << 2))

typedef float f4v __attribute__((ext_vector_type(4)));

// 8 x global_load_dwordx4 -> 32 floats resident (compiler cannot remat asm)
#define LOAD_W8(w, base)                                                   \
    asm volatile(                                                          \
        "global_load_dwordx4 %0, %8, off\n\t"                             \
        "global_load_dwordx4 %1, %8, off offset:16\n\t"                   \
        "global_load_dwordx4 %2, %8, off offset:32\n\t"                   \
        "global_load_dwordx4 %3, %8, off offset:48\n\t"                   \
        "global_load_dwordx4 %4, %8, off offset:64\n\t"                   \
        "global_load_dwordx4 %5, %8, off offset:80\n\t"                   \
        "global_load_dwordx4 %6, %8, off offset:96\n\t"                   \
        "global_load_dwordx4 %7, %8, off offset:112\n\t"                  \
        "s_waitcnt vmcnt(0)"                                               \
        : "=&v"(w[0]), "=&v"(w[1]), "=&v"(w[2]), "=&v"(w[3]),              \
          "=&v"(w[4]), "=&v"(w[5]), "=&v"(w[6]), "=&v"(w[7])               \
        : "v"(base)                                                        \
        : "memory")

// 32-k partial dot against pre-loaded h registers (params avoid x/y/z/w tokens)
#define DOT32R(dst_, warr_, hvarr_)                                        \
    {                                                                      \
        float d0_ = 0.f, d1_ = 0.f;                                        \
        _Pragma("unroll")                                                  \
        for (int j_ = 0; j_ < 8; j_++) {                                   \
            d0_ = fmaf(warr_[j_].x, hvarr_[j_].x, d0_);                    \
            d1_ = fmaf(warr_[j_].y, hvarr_[j_].y, d1_);                    \
            d0_ = fmaf(warr_[j_].z, hvarr_[j_].z, d0_);                    \
            d1_ = fmaf(warr_[j_].w, hvarr_[j_].w, d1_);                    \
        }                                                                  \
        dst_ = d0_ + d1_;                                                  \
    }

// ---------------- device helpers ----------------
__device__ __forceinline__ float sigmoid_(float x) {
    x = fminf(fmaxf(x, -30.f), 30.f);
    return 1.f / (1.f + __expf(-x));
}
__device__ __forceinline__ float tanh_(float x) {
    float ax = fminf(fabsf(x), 15.f);
    float e = __expf(2.f * ax);
    float t = 1.f - 2.f / (e + 1.f);
    return copysignf(t, x);
}
__device__ __forceinline__ void wait_ge_(int* p, int v) {
    if (__hip_atomic_load(p, __ATOMIC_RELAXED, __HIP_MEMORY_SCOPE_AGENT) < v) {
        do { __builtin_amdgcn_s_sleep(1); }
        while (__hip_atomic_load(p, __ATOMIC_RELAXED, __HIP_MEMORY_SCOPE_AGENT) < v);
    }
    (void)__hip_atomic_load(p, __ATOMIC_ACQUIRE, __HIP_MEMORY_SCOPE_AGENT);
}

// ---------------- head: per-(b,d) raw stats over T ----------------
__global__ __launch_bounds__(512) void stats_bd(const float* __restrict__ x,
                                                float* __restrict__ sum_bd,
                                                float* __restrict__ sq_bd) {
    int b = blockIdx.x;
    int tid = threadIdx.x;
    int d = tid & 127, r = tid >> 7;
    const float* xb = x + (size_t)b * T_ * D_;
    float s = 0.f, q = 0.f;
    for (int t = r; t < T_; t += 4) {
        float v = xb[t * D_ + d];
        s += v; q += v * v;
    }
    __shared__ float ls[512], lq[512];
    ls[tid] = s; lq[tid] = q;
    __syncthreads();
    if (r == 0) {
        s = ls[d] + ls[d + 128] + ls[d + 256] + ls[d + 384];
        q = lq[d] + lq[d + 128] + lq[d + 256] + lq[d + 384];
        sum_bd[b * 128 + d] = s;
        sq_bd[b * 128 + d] = q;
    }
}

// fused factors: xn[b,t,d] = (x - mu_bd) * invn  (global detached norm + IN)
__global__ __launch_bounds__(128) void stats_norm(const float* __restrict__ sum_bd,
                                                  const float* __restrict__ sq_bd,
                                                  float* __restrict__ mu_bd,
                                                  float* __restrict__ invn) {
    int d = threadIdx.x;
    float s = 0.f, q = 0.f;
    for (int b = 0; b < B_; b++) { s += sum_bd[b * 128 + d]; q += sq_bd[b * 128 + d]; }
    float n = (float)(B_ * T_);
    float m = s / n;
    float varu = (q - n * m * m) / (n - 1.f);
    float sd = sqrtf(fmaxf(varu, 0.f)) + EPS_;
    for (int b = 0; b < B_; b++) {
        float mu = sum_bd[b * 128 + d] * (1.f / T_);
        float varT = sq_bd[b * 128 + d] * (1.f / T_) - mu * mu;
        mu_bd[b * 128 + d] = mu;
        invn[b * 128 + d] = rsqrtf(fmaxf(varT, 0.f) + EPS_ * sd * sd);
    }
}

// ---------------- scan + riders (everything pipeline-shaped lives here) ---------
// 160 WGs x 512 thr:
//   wg[0..63]    rec(l = wg>>4, b = wg&15): reads ring[l], publishes flag_h[l]
//   wg[64..127]  xproj(l = (wg-64)>>4, b): l==0 reads normalized x (no wait),
//                l>0 reads h_glob[l-1] on flag_h[l-1]; fills ring[l]
//   wg[128..143] px rider: px[b] = norm(x[b]) @ proj_x_w^T + b, + px IN stats
//   wg[144..159] h3-stats rider: IN stats of layer-3 h, chunk-incremental
__global__ __attribute__((amdgpu_waves_per_eu(2, 2))) __launch_bounds__(512)
void scan_pipe6(const float* __restrict__ x,
                const float* __restrict__ Wih, const float* __restrict__ Whh,
                const float* __restrict__ bih, const float* __restrict__ bhh,
                const float* __restrict__ proj_x_w, const float* __restrict__ proj_x_b,
                const float* __restrict__ mu_bd, const float* __restrict__ invn,
                float* __restrict__ h_glob,        // [L][B][T][H]
                float* __restrict__ ring,          // [4][B][4][C_][G]
                float* __restrict__ px,            // [B][T][H]
                float* __restrict__ mu_px, float* __restrict__ inv_px,
                float* __restrict__ mu_ln, float* __restrict__ inv_ln,
                int* __restrict__ flag_h,          // [4][B]
                int* __restrict__ flag_g) {        // [4][B]
    const int wg = blockIdx.x;
    const int tid = threadIdx.x;
    __shared__ __align__(16) float shbuf[16 * HROW_];   // 9216 B, shared by all roles

    if (wg < 64) {
        // ======== recurrent consumer (l, b) — uniform across layers ========
        const int r = tid >> 2, q = tid & 3;
        const int l = wg >> 4, b = wg & 15;
        f4v w0[8], w1[8], w2[8], w3[8];
        const float* wl = Whh + (size_t)l * G_ * 128;
        LOAD_W8(w0, wl + ((size_t)(0 * 128 + r)) * 128 + q * 32);
        LOAD_W8(w1, wl + ((size_t)(1 * 128 + r)) * 128 + q * 32);
        LOAD_W8(w2, wl + ((size_t)(2 * 128 + r)) * 128 + q * 32);
        LOAD_W8(w3, wl + ((size_t)(3 * 128 + r)) * 128 + q * 32);
        float c = 0.f;
        if (tid < HROW_) shbuf[tid] = 0.f;               // h buffer 0
        const float* rsl = ring + ((size_t)l * 16 + b) * (4 * C_ * G_);
        float* hob = h_glob + ((size_t)l * 16 + b) * T_ * 128;
        int* fg = flag_g + l * 16 + b;
        int* fh = flag_h + l * 16 + b;
        float hreg[C_];
        __syncthreads();

        for (int k = 0; k < NCHUNK_; k++) {
            if (tid == 0) wait_ge_(fg, k + 1);
            __syncthreads();
#pragma unroll
            for (int half = 0; half < 2; half++) {
                float p0[8], p1[8], p2[8], p3[8];
#pragma unroll
                for (int s8 = 0; s8 < 8; s8++) {
                    int s = half * 8 + s8;
                    const float* gp = rsl + ((size_t)(k & 3) * C_ + s) * G_;
                    p0[s8] = __hip_atomic_load(gp + r, __ATOMIC_RELAXED, __HIP_MEMORY_SCOPE_AGENT);
                    p1[s8] = __hip_atomic_load(gp + 128 + r, __ATOMIC_RELAXED, __HIP_MEMORY_SCOPE_AGENT);
                    p2[s8] = __hip_atomic_load(gp + 256 + r, __ATOMIC_RELAXED, __HIP_MEMORY_SCOPE_AGENT);
                    p3[s8] = __hip_atomic_load(gp + 384 + r, __ATOMIC_RELAXED, __HIP_MEMORY_SCOPE_AGENT);
                }
#pragma unroll
                for (int s8 = 0; s8 < 8; s8++) {
                    int s = half * 8 + s8;
                    int t = k * C_ + s;
                    const f4v* hb4 = (const f4v*)(shbuf + (t & 1) * HROW_ + q * 36);
                    f4v hv[8];
#pragma unroll
                    for (int j = 0; j < 8; j++) hv[j] = hb4[j];
                    float zi, zf, zg, zo;
                    DOT32R(zi, w0, hv);
                    DOT32R(zf, w1, hv);
                    DOT32R(zg, w2, hv);
                    DOT32R(zo, w3, hv);
                    zi += __shfl_xor(zi, 1); zi += __shfl_xor(zi, 2);
                    zf += __shfl_xor(zf, 1); zf += __shfl_xor(zf, 2);
                    zg += __shfl_xor(zg, 1); zg += __shfl_xor(zg, 2);
                    zo += __shfl_xor(zo, 1); zo += __shfl_xor(zo, 2);
                    zi += p0[s8]; zf += p1[s8]; zg += p2[s8]; zo += p3[s8];
                    float ai = sigmoid_(zi), af = sigmoid_(zf);
                    float ag = tanh_(zg),    ao = sigmoid_(zo);
                    c = fmaf(af, c, ai * ag);
                    float hn = ao * tanh_(c);
                    if (q == 0) shbuf[((t + 1) & 1) * HROW_ + HOFF(r)] = hn;
                    hreg[s] = hn;
                    __syncthreads();
                }
            }
            if (q == 0) {
#pragma unroll
                for (int s = 0; s < C_; s++)
                    __hip_atomic_store(hob + (size_t)(k * C_ + s) * 128 + r, hreg[s],
                                       __ATOMIC_RELAXED, __HIP_MEMORY_SCOPE_AGENT);
            }
            __syncthreads();
            if (tid == 0) __hip_atomic_store(fh, k + 1, __ATOMIC_RELEASE, __HIP_MEMORY_SCOPE_AGENT);
        }
    } else if (wg < 128) {
        // ======== xproj producer (layers 0..3) ========
        const int r = tid >> 2, q = tid & 3;
        const int l = (wg - 64) >> 4, b = (wg - 64) & 15;
        f4v w0[8], w1[8], w2[8], w3[8];
        const float* wl = Wih + (size_t)l * G_ * 128;
        LOAD_W8(w0, wl + ((size_t)(0 * 128 + r)) * 128 + q * 32);
        LOAD_W8(w1, wl + ((size_t)(1 * 128 + r)) * 128 + q * 32);
        LOAD_W8(w2, wl + ((size_t)(2 * 128 + r)) * 128 + q * 32);
        LOAD_W8(w3, wl + ((size_t)(3 * 128 + r)) * 128 + q * 32);
        float bs0 = bih[l * G_ + r] + bhh[l * G_ + r];
        float bs1 = bih[l * G_ + 128 + r] + bhh[l * G_ + 128 + r];
        float bs2 = bih[l * G_ + 256 + r] + bhh[l * G_ + 256 + r];
        float bs3 = bih[l * G_ + 384 + r] + bhh[l * G_ + 384 + r];
        const float* hsrc = (l > 0) ? h_glob + ((size_t)(l - 1) * 16 + b) * T_ * 128
                                    : x + (size_t)b * T_ * 128;
        // layer-0 staging normalization factors (thread always stages k-col tid&127)
        float muk = 0.f, ivk = 1.f;
        if (l == 0) { muk = mu_bd[b * 128 + (tid & 127)]; ivk = invn[b * 128 + (tid & 127)]; }
        float* rout = ring + ((size_t)l * 16 + b) * (4 * C_ * G_);
        int* fhp = (l > 0) ? flag_h + (l - 1) * 16 + b : flag_h;
        int* fhme = flag_h + l * 16 + b;
        int* fgo = flag_g + l * 16 + b;

        for (int k = 0; k < NCHUNK_; k++) {
            if (tid == 0) {
                if (l > 0) wait_ge_(fhp, k + 1);
                if (k >= 4) wait_ge_(fhme, k - 3);
            }
            __syncthreads();
#pragma unroll
            for (int i = 0; i < 4; i++) {
                int idx = i * 512 + tid;
                float v;
                if (l == 0) {
                    v = hsrc[(size_t)k * C_ * 128 + idx];
                    v = (v - muk) * ivk;
                } else {
                    v = __hip_atomic_load(hsrc + (size_t)k * C_ * 128 + idx,
                                          __ATOMIC_RELAXED, __HIP_MEMORY_SCOPE_AGENT);
                }
                shbuf[(idx >> 7) * HROW_ + HOFF(idx & 127)] = v;
            }
            __syncthreads();
#pragma unroll
            for (int s = 0; s < C_; s++) {
                const f4v* hb4 = (const f4v*)(shbuf + s * HROW_ + q * 36);
                f4v hv[8];
#pragma unroll
                for (int j = 0; j < 8; j++) hv[j] = hb4[j];
                float z0, z1, z2, z3;
                DOT32R(z0, w0, hv);
                DOT32R(z1, w1, hv);
                DOT32R(z2, w2, hv);
                DOT32R(z3, w3, hv);
                z0 += __shfl_xor(z0, 1); z0 += __shfl_xor(z0, 2);
                z1 += __shfl_xor(z1, 1); z1 += __shfl_xor(z1, 2);
                z2 += __shfl_xor(z2, 1); z2 += __shfl_xor(z2, 2);
                z3 += __shfl_xor(z3, 1); z3 += __shfl_xor(z3, 2);
                if (q == 0) {
                    float* ro = rout + ((size_t)(k & 3) * C_ + s) * G_;
                    __hip_atomic_store(ro + r, z0 + bs0, __ATOMIC_RELAXED, __HIP_MEMORY_SCOPE_AGENT);
                    __hip_atomic_store(ro + 128 + r, z1 + bs1, __ATOMIC_RELAXED, __HIP_MEMORY_SCOPE_AGENT);
                    __hip_atomic_store(ro + 256 + r, z2 + bs2, __ATOMIC_RELAXED, __HIP_MEMORY_SCOPE_AGENT);
                    __hip_atomic_store(ro + 384 + r, z3 + bs3, __ATOMIC_RELAXED, __HIP_MEMORY_SCOPE_AGENT);
                }
            }
            __syncthreads();
            if (tid == 0) __hip_atomic_store(fgo, k + 1, __ATOMIC_RELEASE, __HIP_MEMORY_SCOPE_AGENT);
        }
    } else if (wg < 144) {
        // ======== px rider: px[b] = norm(x[b]) @ proj_x_w^T + b; + IN stats ========
        const int b = wg - 128;
        const int h = tid & 127, tq = tid >> 7;
        f4v w0[8], w1[8], w2[8], w3[8];
        LOAD_W8(w0, proj_x_w + (size_t)h * 128 + 0);
        LOAD_W8(w1, proj_x_w + (size_t)h * 128 + 32);
        LOAD_W8(w2, proj_x_w + (size_t)h * 128 + 64);
        LOAD_W8(w3, proj_x_w + (size_t)h * 128 + 96);
        float bsx = proj_x_b[h];
        float muk = mu_bd[b * 128 + h], ivk = invn[b * 128 + h];
        const float* xb = x + (size_t)b * T_ * 128;
        float* pxb = px + (size_t)b * T_ * 128;
        float sacc = 0.f, qacc = 0.f;

        for (int blk = 0; blk < 16; blk++) {
            int t0 = blk * 16;
            __syncthreads();
#pragma unroll
            for (int j = 0; j < 4; j++) {
                int tt = tq * 4 + j;
                float v = xb[(size_t)(t0 + tt) * 128 + h];
                shbuf[tt * HROW_ + HOFF(h)] = (v - muk) * ivk;
            }
            __syncthreads();
#pragma unroll
            for (int j = 0; j < 4; j++) {
                int tt = tq * 4 + j;
                const float* row = shbuf + tt * HROW_;
                f4v hv[8];
                float p0, p1, p2, p3;
                const f4v* r4 = (const f4v*)(row + 0 * 36);
#pragma unroll
                for (int u = 0; u < 8; u++) hv[u] = r4[u];
                DOT32R(p0, w0, hv);
                r4 = (const f4v*)(row + 1 * 36);
#pragma unroll
                for (int u = 0; u < 8; u++) hv[u] = r4[u];
                DOT32R(p1, w1, hv);
                r4 = (const f4v*)(row + 2 * 36);
#pragma unroll
                for (int u = 0; u < 8; u++) hv[u] = r4[u];
                DOT32R(p2, w2, hv);
                r4 = (const f4v*)(row + 3 * 36);
#pragma unroll
                for (int u = 0; u < 8; u++) hv[u] = r4[u];
                DOT32R(p3, w3, hv);
                float val = (p0 + p1) + (p2 + p3) + bsx;
                pxb[(size_t)(t0 + tt) * 128 + h] = val;
                sacc += val; qacc += val * val;
            }
        }
        __syncthreads();
        shbuf[tq * 128 + h] = sacc;
        shbuf[512 + tq * 128 + h] = qacc;
        __syncthreads();
        if (tq == 0) {
            float s = shbuf[h] + shbuf[128 + h] + shbuf[256 + h] + shbuf[384 + h];
            float qq = shbuf[512 + h] + shbuf[640 + h] + shbuf[768 + h] + shbuf[896 + h];
            float m = s * (1.f / T_);
            float v = qq * (1.f / T_) - m * m;
            mu_px[b * 128 + h] = m;
            inv_px[b * 128 + h] = rsqrtf(fmaxf(v, 0.f) + EPS_);
        }
    } else {
        // ======== h3-stats rider: IN stats of layer-3 h, chunk-incremental ========
        const int b = wg - 144;
        const int h = tid & 127, st = tid >> 7;
        const float* hsrc = h_glob + ((size_t)3 * 16 + b) * T_ * 128;
        int* f3 = flag_h + 3 * 16 + b;
        float s = 0.f, q = 0.f;
        for (int k = 0; k < NCHUNK_; k++) {
            if (tid == 0) wait_ge_(f3, k + 1);
            __syncthreads();
#pragma unroll
            for (int j = 0; j < 4; j++) {
                int tt = st * 4 + j;
                float v = __hip_atomic_load(hsrc + (size_t)(k * C_ + tt) * 128 + h,
                                            __ATOMIC_RELAXED, __HIP_MEMORY_SCOPE_AGENT);
                s += v; q += v * v;
            }
        }
        shbuf[st * 128 + h] = s;
        shbuf[512 + st * 128 + h] = q;
        __syncthreads();
        if (st == 0) {
            float ss = shbuf[h] + shbuf[128 + h] + shbuf[256 + h] + shbuf[384 + h];
            float qq = shbuf[512 + h] + shbuf[640 + h] + shbuf[768 + h] + shbuf[896 + h];
            float m = ss * (1.f / T_);
            float v = qq * (1.f / T_) - m * m;
            mu_ln[b * 128 + h] = m;
            inv_ln[b * 128 + h] = rsqrtf(fmaxf(v, 0.f) + EPS_);
        }
    }
}

// ---------------- ph GEMM (IN fused on load) + per-row attention score ----------
// 64 blocks x 256 thr: block computes ph tile [64 rows x 128 cols], writes ph,
// then reduces score[row] = sum_h tanh(ph + IN(px)) * attn_w into lsc.
__global__ __launch_bounds__(256) void gemm_score(const float* __restrict__ A,   // h3
                                                  const float* __restrict__ mu,
                                                  const float* __restrict__ inv,
                                                  const float* __restrict__ Bw,  // proj_h_w [128][128]
                                                  const float* __restrict__ b1,
                                                  const float* __restrict__ px,
                                                  const float* __restrict__ mu_px,
                                                  const float* __restrict__ inv_px,
                                                  const float* __restrict__ attn_w,
                                                  float* __restrict__ ph,
                                                  float* __restrict__ lsc) {
    __shared__ __align__(16) float As[16][64];
    __shared__ __align__(16) float Bs[16][128];
    __shared__ float red[64][17];
    int tid = threadIdx.x;
    int m0 = blockIdx.x * 64;
    int lr = tid >> 2, lc = (tid & 3) << 2;          // A staging: row, k-offset
    int lrB = tid >> 1, lcB = (tid & 1) << 3;        // B staging: row(n), k-offset
    int tr = tid >> 4, tc = tid & 15;                // thread tile: 4 rows x 8 cols
    int tm = tr << 2, tn = tc << 3;
    float acc[4][8] = {};
    int bidx = (m0 + lr) >> 8;
    const float* Arow = A + (size_t)(m0 + lr) * 128 + lc;
    const float* mup = mu + bidx * 128 + lc;
    const float* ivp = inv + bidx * 128 + lc;
    const float* Brow = Bw + (size_t)lrB * 128 + lcB;
    for (int kb = 0; kb < 128; kb += 16) {
        float4 av = *(const float4*)(Arow + kb);
        float4 m4 = *(const float4*)(mup + kb);
        float4 i4 = *(const float4*)(ivp + kb);
        av.x = (av.x - m4.x) * i4.x; av.y = (av.y - m4.y) * i4.y;
        av.z = (av.z - m4.z) * i4.z; av.w = (av.w - m4.w) * i4.w;
        float4 bv0 = *(const float4*)(Brow + kb);
        float4 bv1 = *(const float4*)(Brow + kb + 4);
        __syncthreads();
        As[lc + 0][lr] = av.x; As[lc + 1][lr] = av.y; As[lc + 2][lr] = av.z; As[lc + 3][lr] = av.w;
        Bs[lcB + 0][lrB] = bv0.x; Bs[lcB + 1][lrB] = bv0.y; Bs[lcB + 2][lrB] = bv0.z; Bs[lcB + 3][lrB] = bv0.w;
        Bs[lcB + 4][lrB] = bv1.x; Bs[lcB + 5][lrB] = bv1.y; Bs[lcB + 6][lrB] = bv1.z; Bs[lcB + 7][lrB] = bv1.w;
        __syncthreads();
#pragma unroll
        for (int k = 0; k < 16; k++) {
            float ar[4], br[8];
#pragma unroll
            for (int i = 0; i < 4; i++) ar[i] = As[k][tm + i];
#pragma unroll
            for (int j = 0; j < 8; j++) br[j] = Bs[k][tn + j];
#pragma unroll
            for (int i = 0; i < 4; i++)
#pragma unroll
                for (int j = 0; j < 8; j++)
                    acc[i][j] = fmaf(ar[i], br[j], acc[i][j]);
        }
    }
    // epilogue: write ph + score partials
    float spart[4];
#pragma unroll
    for (int i = 0; i < 4; i++) {
        int row = m0 + tm + i;
        int bb = row >> 8;
        float sp = 0.f;
#pragma unroll
        for (int j = 0; j < 8; j++) {
            int col = tn + j;
            float val = acc[i][j] + b1[col];
            ph[(size_t)row * 128 + col] = val;
            float inx = (px[(size_t)row * 128 + col] - mu_px[bb * 128 + col]) * inv_px[bb * 128 + col];
            sp = fmaf(tanh_(val + inx), attn_w[col], sp);
        }
        spart[i] = sp;
    }
    __syncthreads();
#pragma unroll
    for (int i = 0; i < 4; i++) red[tm + i][tc] = spart[i];
    __syncthreads();
    if (tid < 64) {
        float s = 0.f;
#pragma unroll
        for (int j = 0; j < 16; j++) s += red[tid][j];
        lsc[m0 + tid] = s;
    }
}

// ---------------- tail3: softmax + attention map + classify (16 WGs) ----------------
__global__ __launch_bounds__(256) void tail3(const float* __restrict__ lsc,
                                             const float* __restrict__ ph,
                                             const float* __restrict__ fc_w,
                                             const float* __restrict__ fc_b,
                                             float* __restrict__ out,
                                             float* __restrict__ out_att) {
    int b = blockIdx.x;
    int tid = threadIdx.x;
    int h = tid & 127, st = tid >> 7;
    const float* phb = ph + (size_t)b * T_ * H_;
    __shared__ float tmp[256], wsh[256], ls[256];
    float v = lsc[b * 256 + tid];
    tmp[tid] = v; __syncthreads();
    for (int off = 128; off > 0; off >>= 1) { if (tid < off) tmp[tid] = fmaxf(tmp[tid], tmp[tid + off]); __syncthreads(); }
    float mx = tmp[0]; __syncthreads();
    float e = __expf(v - mx);
    tmp[tid] = e; __syncthreads();
    for (int off = 128; off > 0; off >>= 1) { if (tid < off) tmp[tid] += tmp[tid + off]; __syncthreads(); }
    wsh[tid] = e / tmp[0];
    __syncthreads();
    {   // attention map: alpha = softmax_t / D, constant across d
        float* ob = out_att + (size_t)b * T_ * D_;
        const float invD = 1.f / (float)D_;
        for (int i = tid; i < T_ * D_; i += 256) ob[i] = wsh[i >> 7] * invD;
    }
    {   // context + FC
        float acc = 0.f;
        for (int t = st; t < T_; t += 2) acc = fmaf(phb[t * 128 + h], wsh[t], acc);
        ls[tid] = acc;
        __syncthreads();
        if (tid < 128) ls[tid] = ls[tid] + ls[tid + 128];
        __syncthreads();
        if (tid < NC_) {
            float s = fc_b[tid];
            const float* fw = fc_w + tid * 128;
            for (int k = 0; k < 128; k++) s = fmaf(ls[k], fw[k], s);
            out[b * NC_ + tid] = s;
        }
    }
}

// ---------------- launcher ----------------
extern "C" void kernel_launch(void* const* d_in, const int* in_sizes, int n_in,
                              void* d_out, int out_size, void* d_ws, size_t ws_size,
                              hipStream_t stream) {
    const float* x        = (const float*)d_in[0];
    const float* Wih      = (const float*)d_in[1];
    const float* Whh      = (const float*)d_in[2];
    const float* bih      = (const float*)d_in[3];
    const float* bhh      = (const float*)d_in[4];
    const float* proj_h_w = (const float*)d_in[5];
    const float* proj_h_b = (const float*)d_in[6];
    const float* proj_x_w = (const float*)d_in[7];
    const float* proj_x_b = (const float*)d_in[8];
    const float* attn_w   = (const float*)d_in[9];
    const float* fc_w     = (const float*)d_in[10];
    const float* fc_b     = (const float*)d_in[11];
    float* out = (float*)d_out;

    float* ws = (float*)d_ws;
    const size_t NTD = (size_t)B_ * T_ * D_;       // 524288
    float* h_glob = ws;                            // 4*NTD
    float* ring   = h_glob + 4 * NTD;              // 4*NTD (4*16*4*16*512)
    float* px     = ring + 4 * NTD;                // 1*NTD
    float* smalls = px + NTD;
    float* sum_bd = smalls;
    float* sq_bd  = sum_bd + 2048;
    float* mu_bd  = sq_bd + 2048;
    float* invn   = mu_bd + 2048;
    float* mu_ln  = invn + 2048;
    float* inv_ln = mu_ln + 2048;
    float* mu_px  = inv_ln + 2048;
    float* inv_px = mu_px + 2048;
    float* lsc    = inv_px + 2048;
    int*   flags  = (int*)(lsc + 4096);
    int*   flag_h = flags;                         // [64]
    int*   flag_g = flags + 64;                    // [64]
    // post-scan reuse: ph takes layer-0 h area
    float* ph = h_glob;
    const float* h3 = h_glob + 3 * NTD;

    hipMemsetAsync((void*)flags, 0, 128 * sizeof(int), stream);

    // head: stats + fused-normalization factors (tiny)
    stats_bd<<<16, 512, 0, stream>>>(x, sum_bd, sq_bd);
    stats_norm<<<1, 128, 0, stream>>>(sum_bd, sq_bd, mu_bd, invn);

    // the whole pipeline-shaped middle: 4-layer LSTM + all riders
    scan_pipe6<<<160, 512, 0, stream>>>(x, Wih, Whh, bih, bhh,
                                        proj_x_w, proj_x_b, mu_bd, invn,
                                        h_glob, ring, px, mu_px, inv_px,
                                        mu_ln, inv_ln, flag_h, flag_g);

    // ph = IN(h3) @ proj_h_w^T + b, fused with attention scores
    gemm_score<<<64, 256, 0, stream>>>(h3, mu_ln, inv_ln, proj_h_w, proj_h_b,
                                       px, mu_px, inv_px, attn_w, ph, lsc);

    // softmax + attention map + classify
    tail3<<<16, 256, 0, stream>>>(lsc, ph, fc_w, fc_b, out, out + B_ * NC_);
}